// Round 7
// baseline (231377.759 us; speedup 1.0000x reference)
//
#include <hip/hip_runtime.h>
#include <stdint.h>

#define BATCH 4096
#define RNN   512
#define SEGS  512

typedef __attribute__((ext_vector_type(8))) short bf16x8;
typedef __attribute__((ext_vector_type(4))) float f32x4;

#define MODE_TANH  0
#define MODE_BASE  1

// cached staging (prologue GEMM only)
#define GLD_LDS16(g, l) \
  __builtin_amdgcn_global_load_lds((const __attribute__((address_space(1))) void*)(g), \
                                   (__attribute__((address_space(3))) void*)(l), 16, 0, 0)

__device__ __forceinline__ unsigned short f2bf(float f){
  unsigned u = __float_as_uint(f);
  u += 0x7FFF + ((u >> 16) & 1);   // RNE
  return (unsigned short)(u >> 16);
}
__device__ __forceinline__ float bf2f(unsigned short s){
  return __uint_as_float(((unsigned)s) << 16);
}
__device__ __forceinline__ float fsigmoid(float x){ return 1.0f / (1.0f + __expf(-x)); }
__device__ __forceinline__ float ftanh(float x){
  float e = __expf(-2.0f * fabsf(x));
  float t = (1.0f - e) / (1.0f + e);
  return copysignf(t, x);
}

// ---------------- prep kernels ----------------

__global__ void prep_cvt(const float* __restrict__ x, short* __restrict__ y, int n){
  int i = blockIdx.x * 256 + threadIdx.x;
  if (i < n) y[i] = (short)f2bf(x[i]);
}

// W1c (row-major, for prologue GEMM) + per-gate-col scalars.
// Gate reorder: new col 4*j+g <- old row g*512+j  (gate order i,f,g,o)
__global__ void prep_reorder(
    const float* __restrict__ W_ih1,
    const float* __restrict__ b_ih1, const float* __restrict__ b_hh1,
    const float* __restrict__ b_ih2, const float* __restrict__ b_hh2,
    short* __restrict__ W1c,
    float* __restrict__ w1r, float* __restrict__ b1r, float* __restrict__ b2r)
{
  int idx = blockIdx.x * 256 + threadIdx.x;   // over 2048*512
  if (idx >= 2048 * 512) return;
  int rn = idx >> 9;        // new col
  int k  = idx & 511;
  int j = rn >> 2, g = rn & 3;
  int ro = g * 512 + j;     // old row
  W1c[idx] = (short)f2bf(W_ih1[(size_t)ro * 514 + k]);   // W_ih1 rows are length 514
  if (k == 0){
    w1r[rn] = W_ih1[(size_t)ro * 514 + 512];  // the "angles" input column
    b1r[rn] = b_ih1[ro] + b_hh1[ro];
    b2r[rn] = b_ih2[ro] + b_hh2[ro];
  }
}

// Fragment-contiguous weights for the scan (B-frag of mfma_16x16x32_bf16):
// frag(kf, cbf): lane l holds W[col = cbf*16 + (l&15)][k = kf*32 + (l>>4)*8 .. +8]
// layout: frag index = kf*128 + cbf, 512 shorts (1KB) per frag, lane-contiguous.
__global__ void prep_wf1(const float* __restrict__ W_hh1, short* __restrict__ Wf1){
  int idx = blockIdx.x * 256 + threadIdx.x;   // over 2048*512
  if (idx >= 2048 * 512) return;
  int frag = idx >> 9, within = idx & 511;
  int lane = within >> 3, e = within & 7;
  int kf = frag >> 7, cbf = frag & 127;
  int col = cbf * 16 + (lane & 15);
  int k   = kf * 32 + (lane >> 4) * 8 + e;
  int j = col >> 2, g = col & 3;
  int ro = g * 512 + j;
  Wf1[idx] = (short)f2bf(W_hh1[(size_t)ro * 512 + k]);
}

// cell2 weights merged K-wise: kf 0..15 -> W_ih2 (A=h1'), kf 16..31 -> W_hh2 (A=h2)
__global__ void prep_wf2(const float* __restrict__ W_ih2, const float* __restrict__ W_hh2,
                         short* __restrict__ Wf2){
  int idx = blockIdx.x * 256 + threadIdx.x;   // over 4096*512
  if (idx >= 4096 * 512) return;
  int frag = idx >> 9, within = idx & 511;
  int lane = within >> 3, e = within & 7;
  int kf = frag >> 7, cbf = frag & 127;
  int col = cbf * 16 + (lane & 15);
  int j = col >> 2, g = col & 3;
  int ro = g * 512 + j;
  int kk = (kf & 15) * 32 + (lane >> 4) * 8 + e;
  float v = (kf < 16) ? W_ih2[(size_t)ro * 512 + kk] : W_hh2[(size_t)ro * 512 + kk];
  Wf2[idx] = (short)f2bf(v);
}

// head weights, fragment order: 16 frags (kf), cols 0-4 Wmu, 5-9 Wvar, 10-14 Wmix, 15 zero
__global__ void prep_wheadf(const float* __restrict__ Wmu, const float* __restrict__ Wvar,
                            const float* __restrict__ Wmix, short* __restrict__ Wh){
  int idx = blockIdx.x * 256 + threadIdx.x;   // 16*512
  if (idx >= 16 * 512) return;
  int frag = idx >> 9, within = idx & 511;
  int lane = within >> 3, e = within & 7;
  int n = lane & 15;
  int k = frag * 32 + (lane >> 4) * 8 + e;
  float v = (n < 5) ? Wmu[n * 512 + k] : (n < 10) ? Wvar[(n - 5) * 512 + k]
          : (n < 15) ? Wmix[(n - 10) * 512 + k] : 0.f;
  Wh[idx] = (short)f2bf(v);
}

// ---------------- fused bf16 MFMA GEMM (prologue TANH/BASE only) ----------------
// MODE_TANH: row-major bf16 out. MODE_BASE: C-fragment layout out:
//   frag(rb, cbf) = 256 shorts; lane l holds rows rb*16+(l>>4)*4..+4, col cbf*16+(l&15)
__global__ __launch_bounds__(256) void gemm_fused(
    const short* __restrict__ A1, const short* __restrict__ B1,
    int k1, int N, int mode,
    const float* __restrict__ bias,
    void* __restrict__ outp)
{
  __shared__ __align__(16) short As[8192];
  __shared__ __align__(16) short Bs[8192];

  const int tid  = threadIdx.x;
  const int lane = tid & 63;
  const int wave = tid >> 6;
  const int wm = wave >> 1, wn = wave & 1;
  const int m0 = blockIdx.y * 128, n0 = blockIdx.x * 128;

  int aoff[4], boff[4];
  #pragma unroll
  for (int j = 0; j < 4; j++){
    int c = (wave * 4 + j) * 64 + lane;
    int quad = c & 3, r16 = (c >> 2) & 15, kw = (c >> 6) & 1, g = c >> 7;
    int row = g * 16 + r16, col = kw * 32 + quad * 8;
    aoff[j] = (m0 + row) * 512 + col;
    boff[j] = (n0 + row) * 512 + col;
  }

  f32x4 acc[4][4];
  #pragma unroll
  for (int i = 0; i < 4; i++)
    #pragma unroll
    for (int j = 0; j < 4; j++)
      acc[i][j] = (f32x4){0.f, 0.f, 0.f, 0.f};

  const int nk = k1 >> 6;

  auto stage = [&](int it){
    int kk = it << 6;
    #pragma unroll
    for (int j = 0; j < 4; j++){
      GLD_LDS16(A1 + aoff[j] + kk, (char*)As + (wave * 4 + j) * 1024);
      GLD_LDS16(B1 + boff[j] + kk, (char*)Bs + (wave * 4 + j) * 1024);
    }
  };

  const int fro = ((lane & 15) * 4 + (lane >> 4)) * 8;

  auto compute = [&](){
    #pragma unroll
    for (int kw = 0; kw < 2; ++kw){
      bf16x8 af[4], bfr[4];
      #pragma unroll
      for (int f = 0; f < 4; f++){
        af[f]  = *(const bf16x8*)&As[((wm * 4 + f) * 2 + kw) * 512 + fro];
        bfr[f] = *(const bf16x8*)&Bs[((wn * 4 + f) * 2 + kw) * 512 + fro];
      }
      #pragma unroll
      for (int mf = 0; mf < 4; mf++)
        #pragma unroll
        for (int nf = 0; nf < 4; nf++)
          acc[mf][nf] = __builtin_amdgcn_mfma_f32_16x16x32_bf16(af[mf], bfr[nf], acc[mf][nf], 0, 0, 0);
    }
  };

  stage(0);
  __syncthreads();
  compute();
  __syncthreads();
  for (int it = 1; it < nk; ++it){
    stage(it);
    __syncthreads();
    compute();
    __syncthreads();
  }

  const int lr = (lane >> 4) * 4;
  const int lc = lane & 15;
  unsigned short* out = (unsigned short*)outp;
  #pragma unroll
  for (int mf = 0; mf < 4; mf++)
    #pragma unroll
    for (int nf = 0; nf < 4; nf++)
      #pragma unroll
      for (int r = 0; r < 4; r++){
        int grow = m0 + wm * 64 + mf * 16 + lr + r;
        int gcol = n0 + wn * 64 + nf * 16 + lc;
        float v = acc[mf][nf][r] + bias[gcol];
        if (mode == MODE_TANH){
          out[(size_t)grow * N + gcol] = f2bf(ftanh(v));
        } else {
          int rb  = (m0 + wm * 64 + mf * 16) >> 4;
          int cbf = (n0 + wn * 64 + nf * 16) >> 4;
          size_t addr = ((size_t)(rb * 128 + cbf)) * 256 + ((lane >> 4) * 16 + lc) * 4 + r;
          out[addr] = f2bf(v);
        }
      }
}

// ---------------- row-local persistent LSTM scan ----------------
// Block b owns rows [16b,16b+16) for all 512 steps. No cross-block anything.
// h-state LDS (XOR-swizzled, proven R6); c-state VGPRs; weights streamed
// SEQUENTIALLY in fragment order with register double-buffering.
__global__ __launch_bounds__(512, 2) void lstm_block(
    const short* __restrict__ Wf1, const short* __restrict__ Wf2,
    const unsigned short* __restrict__ base1f,
    const float* __restrict__ w1r, const float* __restrict__ b2r,
    const short* __restrict__ Wheadf,
    const float* __restrict__ bmu, const float* __restrict__ bvar, const float* __restrict__ bmix,
    const float* __restrict__ eps, float* __restrict__ fout)
{
  __shared__ __align__(16) short hs[4][8192];  // h1A, h1B, h2A, h2B : [16][512] bf16
  __shared__ float P[256];
  __shared__ float angS[16];

  const int tid  = threadIdx.x;
  const int lane = tid & 63;
  const int wave = tid >> 6;            // 0..7
  const int r0   = blockIdx.x * 16;
  const int lc   = lane & 15;
  const int lr   = (lane >> 4) * 4;
  const int q    = lane & 3;
  const int t4   = (lane >> 2) & 3;
  const int koff = (lane >> 4) * 8;
  const int arow = lane & 15;
  const int lg4  = ((lane >> 4) * 16 + lc) * 4;   // base1f lane offset (shorts)

  for (int i = tid; i < 4 * 8192; i += 512) ((short*)hs)[i] = 0;
  if (tid < 16) angS[tid] = 0.f;
  float c1r[16], c2r[16];
  #pragma unroll
  for (int i = 0; i < 16; i++){ c1r[i] = 0.f; c2r[i] = 0.f; }

  // hoisted per-lane gate scalars (once per kernel, not per step)
  float w1c[16], b2c[16];
  #pragma unroll
  for (int ch = 0; ch < 2; ++ch)
    #pragma unroll
    for (int nf = 0; nf < 8; ++nf){
      int gcol = wave * 256 + ch * 128 + nf * 16 + lc;
      w1c[ch * 8 + nf] = w1r[gcol];
      b2c[ch * 8 + nf] = b2r[gcol];
    }
  __syncthreads();

  // swizzled LDS A-frag read (proven R6)
  auto ldA = [&](const short* h, int k0) -> bf16x8 {
    int a = (arow << 10) | ((k0 + koff) << 1);
    a ^= (arow & 7) << 4;
    return *(const bf16x8*)((const char*)h + a);
  };

  for (int s = 0; s < SEGS; ++s){
    const short* h1i = hs[s & 1];
    short*       h1o = hs[(s & 1) ^ 1];
    const short* h2i = hs[2 + (s & 1)];
    short*       h2o = hs[2 + ((s & 1) ^ 1)];

    // ---- cell1: gates1 = base1 + ang*w1r + h1 @ W^T  (K=512) ----
    #pragma unroll
    for (int ch = 0; ch < 2; ++ch){
      const int cb16 = wave * 16 + ch * 8;   // col-block base (of 128 total)
      uint2 bas[8];                          // base1 frags, in flight under K-loop
      #pragma unroll
      for (int nf = 0; nf < 8; ++nf)
        bas[nf] = *(const uint2*)&base1f[((size_t)blockIdx.x * 128 + cb16 + nf) * 256 + lg4];

      f32x4 acc[8];
      #pragma unroll
      for (int nf = 0; nf < 8; ++nf) acc[nf] = (f32x4){0.f, 0.f, 0.f, 0.f};

      bf16x8 b0[8], b1[8];
      #pragma unroll
      for (int nf = 0; nf < 8; ++nf)
        b0[nf] = *(const bf16x8*)&Wf1[(size_t)(cb16 + nf) * 512 + lane * 8];
      #pragma unroll
      for (int kf = 0; kf < 16; kf += 2){
        #pragma unroll
        for (int nf = 0; nf < 8; ++nf)
          b1[nf] = *(const bf16x8*)&Wf1[(size_t)((kf + 1) * 128 + cb16 + nf) * 512 + lane * 8];
        bf16x8 a0 = ldA(h1i, kf * 32);
        #pragma unroll
        for (int nf = 0; nf < 8; ++nf)
          acc[nf] = __builtin_amdgcn_mfma_f32_16x16x32_bf16(a0, b0[nf], acc[nf], 0, 0, 0);
        if (kf + 2 < 16){
          #pragma unroll
          for (int nf = 0; nf < 8; ++nf)
            b0[nf] = *(const bf16x8*)&Wf1[(size_t)((kf + 2) * 128 + cb16 + nf) * 512 + lane * 8];
        }
        bf16x8 a1 = ldA(h1i, kf * 32 + 32);
        #pragma unroll
        for (int nf = 0; nf < 8; ++nf)
          acc[nf] = __builtin_amdgcn_mfma_f32_16x16x32_bf16(a1, b1[nf], acc[nf], 0, 0, 0);
      }
      #pragma unroll
      for (int nf = 0; nf < 8; ++nf){
        const unsigned short* bp = (const unsigned short*)&bas[nf];
        float vq = 0.f, x1q = 0.f, x2q = 0.f, x3q = 0.f;
        #pragma unroll
        for (int r = 0; r < 4; ++r){
          float v = acc[nf][r] + bf2f(bp[r]) + angS[lr + r] * w1c[ch * 8 + nf];
          float x1 = __shfl_xor(v, 1);
          float x2 = __shfl_xor(v, 2);
          float x3 = __shfl_xor(v, 3);
          if (r == q){ vq = v; x1q = x1; x2q = x2; x3q = x3; }
        }
        float gi = (q == 0) ? vq  : (q == 1) ? x1q : (q == 2) ? x2q : x3q;
        float gf = (q == 0) ? x1q : (q == 1) ? vq  : (q == 2) ? x3q : x2q;
        float gg = (q == 0) ? x2q : (q == 1) ? x3q : (q == 2) ? vq  : x1q;
        float go = (q == 0) ? x3q : (q == 1) ? x2q : (q == 2) ? x1q : vq;
        const int ci = ch * 8 + nf;
        float cn = fsigmoid(gf) * c1r[ci] + fsigmoid(gi) * ftanh(gg);
        float hn = fsigmoid(go) * ftanh(cn);
        c1r[ci] = cn;
        const int row = lr + q;
        const int j   = ((wave * 256 + ch * 128 + nf * 16) >> 2) + t4;
        int wb = ((row << 10) | (j << 1)) ^ ((row & 7) << 4);
        *(unsigned short*)((char*)h1o + wb) = f2bf(hn);
      }
    }
    __syncthreads();   // h1o complete

    // ---- cell2: gates2 = b2r + [h1', h2] @ [W2i;W2h]^T  (K=1024 merged) ----
    #pragma unroll
    for (int ch = 0; ch < 2; ++ch){
      const int cb16 = wave * 16 + ch * 8;
      f32x4 acc[8];
      #pragma unroll
      for (int nf = 0; nf < 8; ++nf) acc[nf] = (f32x4){0.f, 0.f, 0.f, 0.f};

      auto ldA2 = [&](int kf) -> bf16x8 {
        return (kf < 16) ? ldA(h1o, kf * 32) : ldA(h2i, (kf - 16) * 32);
      };
      bf16x8 b0[8], b1[8];
      #pragma unroll
      for (int nf = 0; nf < 8; ++nf)
        b0[nf] = *(const bf16x8*)&Wf2[(size_t)(cb16 + nf) * 512 + lane * 8];
      #pragma unroll
      for (int kf = 0; kf < 32; kf += 2){
        #pragma unroll
        for (int nf = 0; nf < 8; ++nf)
          b1[nf] = *(const bf16x8*)&Wf2[(size_t)((kf + 1) * 128 + cb16 + nf) * 512 + lane * 8];
        bf16x8 a0 = ldA2(kf);
        #pragma unroll
        for (int nf = 0; nf < 8; ++nf)
          acc[nf] = __builtin_amdgcn_mfma_f32_16x16x32_bf16(a0, b0[nf], acc[nf], 0, 0, 0);
        if (kf + 2 < 32){
          #pragma unroll
          for (int nf = 0; nf < 8; ++nf)
            b0[nf] = *(const bf16x8*)&Wf2[(size_t)((kf + 2) * 128 + cb16 + nf) * 512 + lane * 8];
        }
        bf16x8 a1 = ldA2(kf + 1);
        #pragma unroll
        for (int nf = 0; nf < 8; ++nf)
          acc[nf] = __builtin_amdgcn_mfma_f32_16x16x32_bf16(a1, b1[nf], acc[nf], 0, 0, 0);
      }
      #pragma unroll
      for (int nf = 0; nf < 8; ++nf){
        float vq = 0.f, x1q = 0.f, x2q = 0.f, x3q = 0.f;
        #pragma unroll
        for (int r = 0; r < 4; ++r){
          float v = acc[nf][r] + b2c[ch * 8 + nf];
          float x1 = __shfl_xor(v, 1);
          float x2 = __shfl_xor(v, 2);
          float x3 = __shfl_xor(v, 3);
          if (r == q){ vq = v; x1q = x1; x2q = x2; x3q = x3; }
        }
        float gi = (q == 0) ? vq  : (q == 1) ? x1q : (q == 2) ? x2q : x3q;
        float gf = (q == 0) ? x1q : (q == 1) ? vq  : (q == 2) ? x3q : x2q;
        float gg = (q == 0) ? x2q : (q == 1) ? x3q : (q == 2) ? vq  : x1q;
        float go = (q == 0) ? x3q : (q == 1) ? x2q : (q == 2) ? x1q : vq;
        const int ci = ch * 8 + nf;
        float cn = fsigmoid(gf) * c2r[ci] + fsigmoid(gi) * ftanh(gg);
        float hn = fsigmoid(go) * ftanh(cn);
        c2r[ci] = cn;
        const int row = lr + q;
        const int j   = ((wave * 256 + ch * 128 + nf * 16) >> 2) + t4;
        int wb = ((row << 10) | (j << 1)) ^ ((row & 7) << 4);
        *(unsigned short*)((char*)h2o + wb) = f2bf(hn);
      }
    }
    __syncthreads();   // h2o complete

    // ---- head: P = h2' @ Whead^T, then mixture + rsample + tanh ----
    if (wave == 0){
      f32x4 pa = (f32x4){0.f, 0.f, 0.f, 0.f};
      #pragma unroll
      for (int kf = 0; kf < 16; ++kf){
        bf16x8 a = ldA(h2o, kf * 32);
        bf16x8 b = *(const bf16x8*)&Wheadf[(size_t)kf * 512 + lane * 8];
        pa = __builtin_amdgcn_mfma_f32_16x16x32_bf16(a, b, pa, 0, 0, 0);
      }
      #pragma unroll
      for (int r = 0; r < 4; ++r) P[(lr + r) * 16 + lc] = pa[r];
    }
    __syncthreads();   // P visible

    if (wave == 0 && lane < 16){
      float p[15];
      #pragma unroll
      for (int k = 0; k < 15; k++) p[k] = P[lane * 16 + k];
      float l[5], mx = -1e30f;
      #pragma unroll
      for (int k = 0; k < 5; k++){ l[k] = p[10 + k] + bmix[k]; mx = fmaxf(mx, l[k]); }
      float se = 0.f, e[5];
      #pragma unroll
      for (int k = 0; k < 5; k++){ e[k] = __expf(l[k] - mx); se += e[k]; }
      float inv = 1.0f / se, mu = 0.f, sg = 0.f;
      #pragma unroll
      for (int k = 0; k < 5; k++){
        float rho = e[k] * inv;
        mu += rho * (p[k] + bmu[k]);
        sg += rho * __expf(p[5 + k] + bvar[k]);
      }
      float a = ftanh(mu + sg * eps[(size_t)s * BATCH + r0 + lane]);
      angS[lane] = a;
      size_t o = ((size_t)(r0 + lane) * SEGS + s) * 2;
      fout[o] = a; fout[o + 1] = 0.0f;
    }
    __syncthreads();   // angS ready for next step
  }
}

// ---------------- launch ----------------

extern "C" void kernel_launch(void* const* d_in, const int* in_sizes, int n_in,
                              void* d_out, int out_size, void* d_ws, size_t ws_size,
                              hipStream_t stream)
{
  const float* latent   = (const float*)d_in[0];
  const float* W_unpack = (const float*)d_in[1];
  const float* b_unpack = (const float*)d_in[2];
  const float* W_ih1    = (const float*)d_in[3];
  const float* W_hh1    = (const float*)d_in[4];
  const float* b_ih1    = (const float*)d_in[5];
  const float* b_hh1    = (const float*)d_in[6];
  const float* W_ih2    = (const float*)d_in[7];
  const float* W_hh2    = (const float*)d_in[8];
  const float* b_ih2    = (const float*)d_in[9];
  const float* b_hh2    = (const float*)d_in[10];
  const float* W_mu     = (const float*)d_in[11];
  const float* b_mu     = (const float*)d_in[12];
  const float* W_var    = (const float*)d_in[13];
  const float* b_var    = (const float*)d_in[14];
  const float* W_mix    = (const float*)d_in[15];
  const float* b_mix    = (const float*)d_in[16];
  const float* eps      = (const float*)d_in[17];
  float* out = (float*)d_out;

  char* p = (char*)d_ws;
  auto alloc = [&](size_t b) -> void* {
    void* r = (void*)p;
    p += (b + 255) & ~(size_t)255;
    return r;
  };
  short* latb  = (short*)alloc((size_t)BATCH * 512 * 2);
  short* Wub   = (short*)alloc((size_t)512 * 512 * 2);
  short* idea  = (short*)alloc((size_t)BATCH * 512 * 2);
  unsigned short* base1f = (unsigned short*)alloc((size_t)BATCH * 2048 * 2);
  short* W1c    = (short*)alloc((size_t)2048 * 512 * 2);
  short* Wf1    = (short*)alloc((size_t)2048 * 512 * 2);
  short* Wf2    = (short*)alloc((size_t)4096 * 512 * 2);
  short* Wheadf = (short*)alloc((size_t)16 * 512 * 2);
  float* w1r   = (float*)alloc(2048 * 4);
  float* b1r   = (float*)alloc(2048 * 4);
  float* b2r   = (float*)alloc(2048 * 4);

  prep_cvt<<<(BATCH * 512) / 256, 256, 0, stream>>>(latent, latb, BATCH * 512);
  prep_cvt<<<(512 * 512) / 256, 256, 0, stream>>>(W_unpack, Wub, 512 * 512);
  prep_reorder<<<(2048 * 512) / 256, 256, 0, stream>>>(
      W_ih1, b_ih1, b_hh1, b_ih2, b_hh2, W1c, w1r, b1r, b2r);
  prep_wf1<<<(2048 * 512) / 256, 256, 0, stream>>>(W_hh1, Wf1);
  prep_wf2<<<(4096 * 512) / 256, 256, 0, stream>>>(W_ih2, W_hh2, Wf2);
  prep_wheadf<<<32, 256, 0, stream>>>(W_mu, W_var, W_mix, Wheadf);

  dim3 blk(256);
  // idea = tanh(latent @ W_unpack^T + b_unpack)  [bf16, row-major]
  gemm_fused<<<dim3(4, 32), blk, 0, stream>>>(
      latb, Wub, 512, 512, MODE_TANH, b_unpack, (void*)idea);
  // base1 = idea @ W1c^T + (b_ih1 + b_hh1)   [bf16, C-fragment layout]
  gemm_fused<<<dim3(16, 32), blk, 0, stream>>>(
      idea, W1c, 512, 2048, MODE_BASE, b1r, (void*)base1f);

  // whole 512-step scan: 256 independent blocks, 16 rows each, no barriers
  lstm_block<<<256, 512, 0, stream>>>(
      Wf1, Wf2, base1f, w1r, b2r, Wheadf,
      b_mu, b_var, b_mix, eps, out);
}